// Round 15
// baseline (194.301 us; speedup 1.0000x reference)
//
#include <hip/hip_runtime.h>
#include <stdint.h>

typedef short bh8 __attribute__((ext_vector_type(8)));   // 8 x bf16 (bit pattern)
typedef float fx4 __attribute__((ext_vector_type(4)));   // 16x16 MFMA accumulator
typedef float fx16 __attribute__((ext_vector_type(16))); // 32x32 MFMA accumulator
typedef unsigned short u16;
typedef unsigned int u32;
typedef u32 u32x4 __attribute__((ext_vector_type(4)));
typedef u16 us4 __attribute__((ext_vector_type(4)));

#define NHEAD 8
#define HD 64
#define DM 512
#define SEQ 4096
#define ROWS 8192   // B*L = 2*4096
#define CEXP 0.1803368801111244f  /* 0.125 * log2(e): folds 1/sqrt(64) into exp2 */

#define MODE_BF16 1
#define MODE_RELU_BF16 2
#define MODE_KV 3

__device__ __forceinline__ u16 f2bf(float f) {
  union { float f; u32 u; } x; x.f = f;
  u32 u = x.u;
  u = u + 0x7fffu + ((u >> 16) & 1u);   // RNE
  return (u16)(u >> 16);
}
__device__ __forceinline__ float bf2f(u16 h) {
  union { u32 u; float f; } x; x.u = ((u32)h) << 16;
  return x.f;
}
// async global->LDS, 16B per lane. LDS dest = wave-uniform base + lane*16.
__device__ __forceinline__ void gll16(const void* g, void* l) {
  __builtin_amdgcn_global_load_lds(
      (const __attribute__((address_space(1))) void*)(uintptr_t)g,
      (__attribute__((address_space(3))) void*)(uintptr_t)l,
      16, 0, 0);
}
__device__ __forceinline__ fx4 mfma16(bh8 a, bh8 b, fx4 c) {
  return __builtin_amdgcn_mfma_f32_16x16x32_bf16(a, b, c, 0, 0, 0);
}
__device__ __forceinline__ fx16 mfma32(bh8 a, bh8 b, fx16 c) {
  return __builtin_amdgcn_mfma_f32_32x32x16_bf16(a, b, c, 0, 0, 0);
}
__device__ __forceinline__ u32 cvtpk(float lo, float hi) {
  u32 r; asm("v_cvt_pk_bf16_f32 %0, %1, %2" : "=v"(r) : "v"(lo), "v"(hi));
  return r;
}
__device__ __forceinline__ void pswap(u32& a, u32& b) {
  auto r = __builtin_amdgcn_permlane32_swap(a, b, false, false);
  a = r[0]; b = r[1];
}

// fragment-major weight index (us4 units). For weight elem (n,k):
// lane fr=n&15, fg=(k>>3)&3; chunk = (nblk*(K/32)+kblk)*4+fg holds 16 lanes x 8 elems.
__device__ __forceinline__ int fragidx4(int n, int k4, int K) {
  return (((((n >> 4) * (K >> 5) + (k4 >> 5)) << 2) + ((k4 >> 3) & 3)) * 16 + (n & 15)) * 2
         + ((k4 & 7) >> 2);
}

// ---------------- fused fp32 -> bf16 convert; weights -> fragment-major --------
__global__ __launch_bounds__(256) void cvt_all_kernel(
    const float* __restrict__ x, const float* __restrict__ src,
    const float* __restrict__ Wq, const float* __restrict__ Wk,
    const float* __restrict__ Wv, const float* __restrict__ Wm,
    const float* __restrict__ W1, const float* __restrict__ W2,
    u16* __restrict__ xb, u16* __restrict__ sb,
    u16* __restrict__ wqb, u16* __restrict__ wkvb, u16* __restrict__ wmb,
    u16* __restrict__ w1b, u16* __restrict__ w2b) {
  const int NQ = ROWS * DM / 4;  // 1048576 quads per activation tensor
  const int TOT = 2 * NQ + 655360;
  for (int i = blockIdx.x * 256 + threadIdx.x; i < TOT; i += gridDim.x * 256) {
    const float* s; u16* d; int j; int widx = -1;
    if (i < NQ)            { s = x;  d = xb;  j = i; }
    else if (i < 2 * NQ)   { s = src; d = sb; j = i - NQ; }
    else {
      int k = i - 2 * NQ;
      int n, k4, K;
      if (k < 65536)       { s = Wq; d = wqb; j = k;          n = j >> 7; k4 = (j & 127) << 2; K = 512; }
      else if (k < 131072) { s = Wk; d = wkvb; j = k - 65536; n = j >> 7; k4 = (j & 127) << 2; K = 512; }
      else if (k < 196608) { s = Wv; d = wkvb; j = k - 131072; n = (j >> 7) + 512; k4 = (j & 127) << 2; K = 512; }
      else if (k < 262144) { s = Wm; d = wmb; j = k - 196608; n = j >> 7; k4 = (j & 127) << 2; K = 512; }
      else if (k < 524288) { s = W1; d = w1b; j = k - 262144; n = j >> 8; k4 = (j & 255) << 2; K = 1024; }
      else                 { s = W2; d = w2b; j = k - 524288; n = j >> 8; k4 = (j & 255) << 2; K = 1024; }
      widx = fragidx4(n, k4, K);
    }
    float4 v = ((const float4*)s)[j];
    us4 o; o.x = f2bf(v.x); o.y = f2bf(v.y); o.z = f2bf(v.z); o.w = f2bf(v.w);
    ((us4*)d)[widx < 0 ? j : widx] = o;
  }
}

// ---------------- GEMM core: 2-phase double-buffered A, direct-L2 B ------------
template <int NTW>
__device__ __forceinline__ void gemm_core(
    char* smem, const u16* __restrict__ A, const u16* __restrict__ A2, int strideA,
    const u16* __restrict__ Bw, void* __restrict__ Cp, void* __restrict__ C2p,
    int N, int K, int mode, float scl, int bx, int by) {
  const int tid = threadIdx.x;
  const int w = tid >> 6, l = tid & 63;
  const int fr = l & 15, fg = l >> 4;
  const int row0 = by * 128, col0 = bx * NTW * 32;
  const int wr = (w >> 1) * 64, wc = (w & 1) * NTW * 16;

  auto STAGE = [&](int buf, int k0) {
    const u16* Asrc = (k0 < 512) ? A : A2;
    const int kk = k0 & (strideA - 1);
    char* dst = smem + buf * 16384;
#pragma unroll
    for (int i = 0; i < 4; i++) {
      int t = i * 256 + tid;
      int rr = t >> 3, g = t & 7;
      int gs = g ^ (rr & 7);
      gll16(Asrc + (size_t)(row0 + rr) * strideA + kk + gs * 8, dst + i * 4096 + w * 1024);
    }
  };

  fx4 acc[4][NTW];
#pragma unroll
  for (int m = 0; m < 4; m++)
#pragma unroll
    for (int n = 0; n < NTW; n++)
#pragma unroll
      for (int r = 0; r < 4; r++) acc[m][n][r] = 0.f;

  STAGE(0, 0);
  __syncthreads();  // drain: buf0 visible

  const int nk = K / 64;
  for (int ti = 0; ti < nk; ti++) {
    const int k0 = ti * 64;
    bh8 bfr[2][NTW];
#pragma unroll
    for (int ks = 0; ks < 2; ks++)
#pragma unroll
      for (int n = 0; n < NTW; n++) {
        const u16* bp = Bw +
            ((((size_t)((col0 + wc) >> 4) + n) * (K >> 5) + (k0 >> 5) + ks) * 4 + fg) * 128 +
            fr * 8;
        bfr[ks][n] = *(const bh8*)bp;
      }
    if (ti + 1 < nk) STAGE((ti + 1) & 1, k0 + 64);
    const char* sA = smem + (ti & 1) * 16384;
#pragma unroll
    for (int ks = 0; ks < 2; ks++) {
      bh8 af[4];
#pragma unroll
      for (int m = 0; m < 4; m++) {
        int rr = wr + m * 16 + fr;
        af[m] = *(const bh8*)(sA + rr * 128 + ((ks * 64 + fg * 16) ^ ((rr & 7) << 4)));
      }
      __builtin_amdgcn_s_setprio(1);
#pragma unroll
      for (int m = 0; m < 4; m++)
#pragma unroll
        for (int n = 0; n < NTW; n++) acc[m][n] = mfma16(af[m], bfr[ks][n], acc[m][n]);
      __builtin_amdgcn_s_setprio(0);
    }
    __syncthreads();
  }
#pragma unroll
  for (int m = 0; m < 4; m++)
#pragma unroll
    for (int n = 0; n < NTW; n++)
#pragma unroll
      for (int r = 0; r < 4; r++) {
        int row = row0 + wr + m * 16 + fg * 4 + r;
        int col = col0 + wc + n * 16 + fr;
        float v = acc[m][n][r];
        if (mode == MODE_BF16) {
          ((u16*)Cp)[(size_t)row * N + col] = f2bf(v * scl);
        } else if (mode == MODE_RELU_BF16) {
          ((u16*)Cp)[(size_t)row * N + col] = f2bf(v > 0.f ? v : 0.f);
        } else {  // MODE_KV: scatter into fragment-major K2 / V2 layouts
          int bb = row >> 12, s = row & 4095;
          if (col < 512) {
            int h = col >> 6, dd = col & 63;
            ((u16*)Cp)[(((size_t)((bb * 8 + h) * 8 + (dd >> 3))) * SEQ + s) * 8 + (dd & 7)] = f2bf(v);
          } else {
            int dd2 = col - 512;
            int h = dd2 >> 6, dd = dd2 & 63;
            ((u16*)C2p)[(((size_t)((bb * 8 + h) * 512 + (s >> 3))) * 64 + dd) * 8 + (s & 7)] = f2bf(v);
          }
        }
      }
}

// ---------------- fused Q + KV projection (768 blocks, 128x128 tiles) ----------
// T1 XCD placement: by = id % 64 -> same-A-panel blocks land on the same XCD L2.
__global__ __launch_bounds__(256) void qkv_kernel(
    const u16* __restrict__ xb, const u16* __restrict__ sb,
    const u16* __restrict__ wqb, const u16* __restrict__ wkvb,
    u16* __restrict__ Qb, u16* __restrict__ K2, u16* __restrict__ V2) {
  __shared__ __attribute__((aligned(16))) char smem[2 * 16384];
  int bid = blockIdx.x;
  if (bid < 256) {
    gemm_core<4>(smem, xb, xb, 512, wqb, Qb, nullptr, 512, 512, MODE_BF16, CEXP,
                 bid >> 6, bid & 63);
  } else {
    int kb = bid - 256;
    gemm_core<4>(smem, sb, sb, 512, wkvb, K2, V2, 1024, 512, MODE_KV, 1.0f,
                 kb >> 6, kb & 63);
  }
}

// ---------------- FFN1: relu((x|m) @ W1^T), concat-free, 512 blocks ------------
__global__ __launch_bounds__(256) void ffn1_kernel(
    const u16* __restrict__ xb, const u16* __restrict__ m0ln,
    const u16* __restrict__ w1b, u16* __restrict__ h1) {
  __shared__ __attribute__((aligned(16))) char smem[2 * 16384];
  int bid = blockIdx.x;
  gemm_core<4>(smem, xb, m0ln, 512, w1b, h1, nullptr, 1024, 1024, MODE_RELU_BF16, 1.0f,
               bid >> 6, bid & 63);
}

// ---------------- N=512 GEMM (M0, FFN2): 128x64 tiles, 512 blocks --------------
__global__ __launch_bounds__(256) void gemm64_kernel(
    const u16* __restrict__ A, const u16* __restrict__ A2, int strideA,
    const u16* __restrict__ Bw, u16* __restrict__ Cp, int K, float scl) {
  __shared__ __attribute__((aligned(16))) char smem[2 * 16384];
  int bid = blockIdx.x;
  gemm_core<2>(smem, A, A2, strideA, Bw, Cp, nullptr, 512, K, MODE_BF16, scl,
               bid >> 6, bid & 63);
}

// ---------------- flash attention: LDS-free, 2-tile register pipeline ----------
// grid 512 blocks (wave count structurally fixed at 2048 -> 2 waves/SIMD), so
// VGPRs are nearly free (~450 budget). Two DISJOINT register sets (A/B) for
// K/V fragments: while tile-A computes (QK->exp->pack->PV ~1100cy), tile-B's
// 16 loads are in flight with no WAR hazard (round-7's aliased-reg bug fixed).
// Tail loads (t=NT, NT+1) read harmlessly into adjacent workspace, never used.
__global__ __launch_bounds__(256, 2) void attn_kernel(
    const u16* __restrict__ Q, const u16* __restrict__ K2,
    const u16* __restrict__ V2, u16* __restrict__ O) {
  const int tid = threadIdx.x;
  const int w = tid >> 6, l = tid & 63;
  const int l31 = l & 31, hi = l >> 5;

  // XCD c = dl%8 sees only bh in {2c,2c+1} -> KV (4MB) L2-resident per XCD
  int dl = blockIdx.x;
  int c = dl & 7, j = dl >> 3;
  int bh = 2 * c + (j >> 5);
  int qb = j & 31;
  const int b = bh >> 3, h = bh & 7;
  const int qr0 = b * SEQ + qb * 128 + w * 32;
  const int NT = SEQ / 64;

  bh8 qf[4];
#pragma unroll
  for (int ks = 0; ks < 4; ks++)
    qf[ks] = *(const bh8*)(Q + (size_t)(qr0 + l31) * DM + h * HD + ks * 16 + hi * 8);

  const u16* Kbase = K2 + (size_t)bh * 8 * SEQ * 8;   // [slot][s][8d]
  const u16* Vbase = V2 + (size_t)bh * 512 * 64 * 8;  // [sslot][d][8s]

  const u16* kp[4]; const u16* vp[4];
#pragma unroll
  for (int ks = 0; ks < 4; ks++) {
    kp[ks] = Kbase + ((size_t)(ks * 2 + hi) * SEQ + l31) * 8;
    vp[ks] = Vbase + ((size_t)(ks * 2 + hi) * 64 + l31) * 8;
  }

  fx16 o0, o1;
#pragma unroll
  for (int r = 0; r < 16; r++) { o0[r] = 0.f; o1[r] = 0.f; }
  float l_run = 0.f;

  // register double-buffer: set A and set B (disjoint)
  bh8 kA0[4], kA1[4], vA0[4], vA1[4];
  bh8 kB0[4], kB1[4], vB0[4], vB1[4];

#pragma unroll
  for (int ks = 0; ks < 4; ks++) {   // prologue: tile 0 -> set A
    kA0[ks] = *(const bh8*)kp[ks];
    kA1[ks] = *(const bh8*)(kp[ks] + 256);
    vA0[ks] = *(const bh8*)vp[ks];
    vA1[ks] = *(const bh8*)(vp[ks] + 256);
    kp[ks] += 512; vp[ks] += 4096;
  }

#define ATTN_TILE(kf0, kf1, vf0, vf1, nk0, nk1, nv0, nv1)                      \
  {                                                                            \
    /* issue next tile's loads into the OTHER register set first */            \
    _Pragma("unroll")                                                          \
    for (int ks = 0; ks < 4; ks++) {                                           \
      nk0[ks] = *(const bh8*)kp[ks];                                           \
      nk1[ks] = *(const bh8*)(kp[ks] + 256);                                   \
      nv0[ks] = *(const bh8*)vp[ks];                                           \
      nv1[ks] = *(const bh8*)(vp[ks] + 256);                                   \
      kp[ks] += 512; vp[ks] += 4096;                                           \
    }                                                                          \
    fx16 s0v, s1v;                                                             \
    _Pragma("unroll")                                                          \
    for (int r = 0; r < 16; r++) { s0v[r] = 0.f; s1v[r] = 0.f; }               \
    __builtin_amdgcn_s_setprio(1);                                             \
    _Pragma("unroll")                                                          \
    for (int ks = 0; ks < 4; ks++) {                                           \
      s0v = mfma32(kf0[ks], qf[ks], s0v);                                      \
      s1v = mfma32(kf1[ks], qf[ks], s1v);                                      \
    }                                                                          \
    __builtin_amdgcn_s_setprio(0);                                             \
    float rs = 0.f;                                                            \
    _Pragma("unroll")                                                          \
    for (int r = 0; r < 16; r++) {                                             \
      s0v[r] = __builtin_amdgcn_exp2f(s0v[r]); rs += s0v[r];                   \
    }                                                                          \
    _Pragma("unroll")                                                          \
    for (int r = 0; r < 16; r++) {                                             \
      s1v[r] = __builtin_amdgcn_exp2f(s1v[r]); rs += s1v[r];                   \
    }                                                                          \
    l_run += rs;                                                               \
    __builtin_amdgcn_s_setprio(1);                                             \
    _Pragma("unroll")                                                          \
    for (int ks = 0; ks < 4; ks++) {                                           \
      int o8 = (ks & 1) * 8;                                                   \
      u32 w0a, w1a, w0b, w1b;                                                  \
      if (ks < 2) {                                                            \
        w0a = cvtpk(s0v[o8 + 0], s0v[o8 + 1]);                                 \
        w1a = cvtpk(s0v[o8 + 2], s0v[o8 + 3]);                                 \
        w0b = cvtpk(s0v[o8 + 4], s0v[o8 + 5]);                                 \
        w1b = cvtpk(s0v[o8 + 6], s0v[o8 + 7]);                                 \
      } else {                                                                 \
        w0a = cvtpk(s1v[o8 + 0], s1v[o8 + 1]);                                 \
        w1a = cvtpk(s1v[o8 + 2], s1v[o8 + 3]);                                 \
        w0b = cvtpk(s1v[o8 + 4], s1v[o8 + 5]);                                 \
        w1b = cvtpk(s1v[o8 + 6], s1v[o8 + 7]);                                 \
      }                                                                        \
      pswap(w0a, w0b); pswap(w1a, w1b);                                        \
      u32x4 fw; fw.x = w0a; fw.y = w1a; fw.z = w0b; fw.w = w1b;                \
      bh8 pa = __builtin_bit_cast(bh8, fw);                                    \
      o0 = mfma32(pa, vf0[ks], o0);                                            \
      o1 = mfma32(pa, vf1[ks], o1);                                            \
    }                                                                          \
    __builtin_amdgcn_s_setprio(0);                                             \
  }

  for (int t = 0; t < NT; t += 2) {
    ATTN_TILE(kA0, kA1, vA0, vA1, kB0, kB1, vB0, vB1)   // compute A, load B
    ATTN_TILE(kB0, kB1, vB0, vB1, kA0, kA1, vA0, vA1)   // compute B, load A
  }
#undef ATTN_TILE

  // epilogue: l_run complete (full S) -> normalize and store directly
  l_run += __shfl_xor(l_run, 32);
#pragma unroll
  for (int r = 0; r < 16; r++) {
    int crow = (r & 3) + 8 * (r >> 2) + 4 * hi;
    float li = 1.0f / __shfl(l_run, crow);
    size_t row = (size_t)(qr0 + crow);
    O[row * DM + h * HD + l31] = f2bf(o0[r] * li);
    O[row * DM + h * HD + 32 + l31] = f2bf(o1[r] * li);
  }
}

// ---------------- m0ln = LN(M0)*g1+b1: wave-per-row, row-major bf16 ------------
__global__ __launch_bounds__(256) void ln_kernel(
    const u16* __restrict__ M0, const float* __restrict__ g1,
    const float* __restrict__ b1, u16* __restrict__ out) {
  const int row = blockIdx.x * 4 + (threadIdx.x >> 6);
  const int lane = threadIdx.x & 63;
  bh8 v = *(const bh8*)(M0 + (size_t)row * 512 + lane * 8);
  float f[8], s = 0.f, s2 = 0.f;
#pragma unroll
  for (int j = 0; j < 8; j++) { f[j] = bf2f((u16)v[j]); s += f[j]; s2 += f[j] * f[j]; }
#pragma unroll
  for (int off = 1; off <= 32; off <<= 1) {
    s += __shfl_xor(s, off);
    s2 += __shfl_xor(s2, off);
  }
  float mu = s * (1.f / 512.f);
  float var = s2 * (1.f / 512.f) - mu * mu;
  float rstd = rsqrtf(var + 1e-5f);
  int col = lane * 8;
  bh8 o;
#pragma unroll
  for (int j = 0; j < 8; j++)
    o[j] = (short)f2bf((f[j] - mu) * rstd * g1[col + j] + b1[col + j]);
  *(bh8*)(out + (size_t)row * 512 + col) = o;
}

// ---------------- out = x + LN(f)*g2+b2: wave-per-row, fp32 out ----------------
__global__ __launch_bounds__(256) void ln_res_kernel(
    const u16* __restrict__ F, const float* __restrict__ X,
    const float* __restrict__ g2, const float* __restrict__ b2,
    float* __restrict__ out) {
  const int row = blockIdx.x * 4 + (threadIdx.x >> 6);
  const int lane = threadIdx.x & 63;
  bh8 v = *(const bh8*)(F + (size_t)row * 512 + lane * 8);
  float f[8], s = 0.f, s2 = 0.f;
#pragma unroll
  for (int j = 0; j < 8; j++) { f[j] = bf2f((u16)v[j]); s += f[j]; s2 += f[j] * f[j]; }
#pragma unroll
  for (int off = 1; off <= 32; off <<= 1) {
    s += __shfl_xor(s, off);
    s2 += __shfl_xor(s2, off);
  }
  float mu = s * (1.f / 512.f);
  float var = s2 * (1.f / 512.f) - mu * mu;
  float rstd = rsqrtf(var + 1e-5f);
  int col = lane * 8;
  const float* xr = X + (size_t)row * 512 + col;
  float* orow = out + (size_t)row * 512 + col;
#pragma unroll
  for (int j = 0; j < 8; j++)
    orow[j] = xr[j] + (f[j] - mu) * rstd * g2[col + j] + b2[col + j];
}

extern "C" void kernel_launch(void* const* d_in, const int* in_sizes, int n_in,
                              void* d_out, int out_size, void* d_ws, size_t ws_size,
                              hipStream_t stream) {
  (void)in_sizes; (void)n_in; (void)out_size; (void)ws_size;
  const float* x   = (const float*)d_in[0];
  const float* src = (const float*)d_in[1];
  const float* Wq  = (const float*)d_in[2];
  const float* Wk  = (const float*)d_in[3];
  const float* Wv  = (const float*)d_in[4];
  const float* Wm  = (const float*)d_in[5];
  const float* W1  = (const float*)d_in[6];
  const float* W2  = (const float*)d_in[7];
  const float* g1  = (const float*)d_in[8];
  const float* b1  = (const float*)d_in[9];
  const float* g2  = (const float*)d_in[10];
  const float* b2  = (const float*)d_in[11];

  char* ws = (char*)d_ws;
  u16* xb   = (u16*)(ws + 0);          // row-major bf16 x
  u16* sb   = (u16*)(ws + 8388608);    // row-major bf16 src
  u16* wqb  = (u16*)(ws + 16777216);   // frag-major weights
  u16* wkvb = (u16*)(ws + 17301504);
  u16* wmb  = (u16*)(ws + 18350080);
  u16* w1b  = (u16*)(ws + 18874368);
  u16* w2b  = (u16*)(ws + 20971520);
  u16* Qb   = (u16*)(ws + 22020096);   // row-major Q (pre-scaled by CEXP)
  u16* K2b  = (u16*)(ws + 30408704);   // attn fragment-major K
  u16* V2b  = (u16*)(ws + 38797312);   // attn fragment-major V
  u16* Ob   = (u16*)(ws + 47185920);   // attn output, row-major (normalized)

  u16* M0b  = (u16*)(ws + 30408704);   // aliases K2b (dead after attn)
  u16* m0ln = (u16*)(ws + 38797312);   // aliases V2b (dead after attn)
  u16* h1b  = (u16*)(ws + 22020096);   // 16MB, aliases Qb (dead after attn)
  u16* fb   = (u16*)(ws + 8388608);    // aliases sb (dead after qkv)

  cvt_all_kernel<<<2048, 256, 0, stream>>>(x, src, Wq, Wk, Wv, Wm, W1, W2,
                                           xb, sb, wqb, wkvb, wmb, w1b, w2b);
  qkv_kernel<<<768, 256, 0, stream>>>(xb, sb, wqb, wkvb, Qb, K2b, V2b);
  attn_kernel<<<512, 256, 0, stream>>>(Qb, K2b, V2b, Ob);
  gemm64_kernel<<<512, 256, 0, stream>>>(Ob, Ob, 512, wmb, M0b, 512, 1.0f);
  ln_kernel<<<2048, 256, 0, stream>>>(M0b, g1, b1, m0ln);
  ffn1_kernel<<<512, 256, 0, stream>>>(xb, m0ln, w1b, h1b);
  gemm64_kernel<<<512, 256, 0, stream>>>(h1b, h1b, 1024, w2b, fb, 1024, 1.0f);
  ln_res_kernel<<<2048, 256, 0, stream>>>(fb, x, g2, b2, (float*)d_out);
}

// Round 16
// 190.329 us; speedup vs baseline: 1.0209x; 1.0209x over previous
//
#include <hip/hip_runtime.h>
#include <stdint.h>

typedef short bh8 __attribute__((ext_vector_type(8)));   // 8 x bf16 (bit pattern)
typedef float fx4 __attribute__((ext_vector_type(4)));   // 16x16 MFMA accumulator
typedef float fx16 __attribute__((ext_vector_type(16))); // 32x32 MFMA accumulator
typedef unsigned short u16;
typedef unsigned int u32;
typedef u32 u32x4 __attribute__((ext_vector_type(4)));
typedef u16 us4 __attribute__((ext_vector_type(4)));

#define NHEAD 8
#define HD 64
#define DM 512
#define SEQ 4096
#define ROWS 8192   // B*L = 2*4096
#define CEXP 0.1803368801111244f  /* 0.125 * log2(e): folds 1/sqrt(64) into exp2 */

#define MODE_BF16 1
#define MODE_RELU_BF16 2
#define MODE_KV 3

__device__ __forceinline__ u16 f2bf(float f) {
  union { float f; u32 u; } x; x.f = f;
  u32 u = x.u;
  u = u + 0x7fffu + ((u >> 16) & 1u);   // RNE
  return (u16)(u >> 16);
}
__device__ __forceinline__ float bf2f(u16 h) {
  union { u32 u; float f; } x; x.u = ((u32)h) << 16;
  return x.f;
}
// async global->LDS, 16B per lane. LDS dest = wave-uniform base + lane*16.
__device__ __forceinline__ void gll16(const void* g, void* l) {
  __builtin_amdgcn_global_load_lds(
      (const __attribute__((address_space(1))) void*)(uintptr_t)g,
      (__attribute__((address_space(3))) void*)(uintptr_t)l,
      16, 0, 0);
}
__device__ __forceinline__ fx4 mfma16(bh8 a, bh8 b, fx4 c) {
  return __builtin_amdgcn_mfma_f32_16x16x32_bf16(a, b, c, 0, 0, 0);
}
__device__ __forceinline__ fx16 mfma32(bh8 a, bh8 b, fx16 c) {
  return __builtin_amdgcn_mfma_f32_32x32x16_bf16(a, b, c, 0, 0, 0);
}
__device__ __forceinline__ u32 cvtpk(float lo, float hi) {
  u32 r; asm("v_cvt_pk_bf16_f32 %0, %1, %2" : "=v"(r) : "v"(lo), "v"(hi));
  return r;
}
__device__ __forceinline__ void pswap(u32& a, u32& b) {
  auto r = __builtin_amdgcn_permlane32_swap(a, b, false, false);
  a = r[0]; b = r[1];
}

// fragment-major weight index (us4 units). For weight elem (n,k):
// lane fr=n&15, fg=(k>>3)&3; chunk = (nblk*(K/32)+kblk)*4+fg holds 16 lanes x 8 elems.
__device__ __forceinline__ int fragidx4(int n, int k4, int K) {
  return (((((n >> 4) * (K >> 5) + (k4 >> 5)) << 2) + ((k4 >> 3) & 3)) * 16 + (n & 15)) * 2
         + ((k4 & 7) >> 2);
}

// ---------------- fused fp32 -> bf16 convert; weights -> fragment-major --------
__global__ __launch_bounds__(256) void cvt_all_kernel(
    const float* __restrict__ x, const float* __restrict__ src,
    const float* __restrict__ Wq, const float* __restrict__ Wk,
    const float* __restrict__ Wv, const float* __restrict__ Wm,
    const float* __restrict__ W1, const float* __restrict__ W2,
    u16* __restrict__ xb, u16* __restrict__ sb,
    u16* __restrict__ wqb, u16* __restrict__ wkvb, u16* __restrict__ wmb,
    u16* __restrict__ w1b, u16* __restrict__ w2b) {
  const int NQ = ROWS * DM / 4;  // 1048576 quads per activation tensor
  const int TOT = 2 * NQ + 655360;
  for (int i = blockIdx.x * 256 + threadIdx.x; i < TOT; i += gridDim.x * 256) {
    const float* s; u16* d; int j; int widx = -1;
    if (i < NQ)            { s = x;  d = xb;  j = i; }
    else if (i < 2 * NQ)   { s = src; d = sb; j = i - NQ; }
    else {
      int k = i - 2 * NQ;
      int n, k4, K;
      if (k < 65536)       { s = Wq; d = wqb; j = k;          n = j >> 7; k4 = (j & 127) << 2; K = 512; }
      else if (k < 131072) { s = Wk; d = wkvb; j = k - 65536; n = j >> 7; k4 = (j & 127) << 2; K = 512; }
      else if (k < 196608) { s = Wv; d = wkvb; j = k - 131072; n = (j >> 7) + 512; k4 = (j & 127) << 2; K = 512; }
      else if (k < 262144) { s = Wm; d = wmb; j = k - 196608; n = j >> 7; k4 = (j & 127) << 2; K = 512; }
      else if (k < 524288) { s = W1; d = w1b; j = k - 262144; n = j >> 8; k4 = (j & 255) << 2; K = 1024; }
      else                 { s = W2; d = w2b; j = k - 524288; n = j >> 8; k4 = (j & 255) << 2; K = 1024; }
      widx = fragidx4(n, k4, K);
    }
    float4 v = ((const float4*)s)[j];
    us4 o; o.x = f2bf(v.x); o.y = f2bf(v.y); o.z = f2bf(v.z); o.w = f2bf(v.w);
    ((us4*)d)[widx < 0 ? j : widx] = o;
  }
}

// ---------------- GEMM core: 2-phase double-buffered A, direct-L2 B ------------
// A staged via LDS (2 x 16KB, swizzled): STAGE(t+1) issued BEFORE compute(t),
// one barrier per K-step (T3 minimum 2-phase). B fragments loaded directly from
// fragment-major global (weights L2-resident; 64 lanes x 16B = 1KB contiguous).
// A-source switches at k0=512 (A|A2) for the concat-free FFN1.
template <int NTW>
__device__ __forceinline__ void gemm_core(
    char* smem, const u16* __restrict__ A, const u16* __restrict__ A2, int strideA,
    const u16* __restrict__ Bw, void* __restrict__ Cp, void* __restrict__ C2p,
    int N, int K, int mode, float scl, int bx, int by) {
  const int tid = threadIdx.x;
  const int w = tid >> 6, l = tid & 63;
  const int fr = l & 15, fg = l >> 4;
  const int row0 = by * 128, col0 = bx * NTW * 32;
  const int wr = (w >> 1) * 64, wc = (w & 1) * NTW * 16;

  auto STAGE = [&](int buf, int k0) {
    const u16* Asrc = (k0 < 512) ? A : A2;
    const int kk = k0 & (strideA - 1);
    char* dst = smem + buf * 16384;
#pragma unroll
    for (int i = 0; i < 4; i++) {
      int t = i * 256 + tid;
      int rr = t >> 3, g = t & 7;
      int gs = g ^ (rr & 7);
      gll16(Asrc + (size_t)(row0 + rr) * strideA + kk + gs * 8, dst + i * 4096 + w * 1024);
    }
  };

  fx4 acc[4][NTW];
#pragma unroll
  for (int m = 0; m < 4; m++)
#pragma unroll
    for (int n = 0; n < NTW; n++)
#pragma unroll
      for (int r = 0; r < 4; r++) acc[m][n][r] = 0.f;

  STAGE(0, 0);
  __syncthreads();  // drain: buf0 visible

  const int nk = K / 64;
  for (int ti = 0; ti < nk; ti++) {
    const int k0 = ti * 64;
    // B fragments for this tile: direct from global (L2-hit), needed soonest
    bh8 bfr[2][NTW];
#pragma unroll
    for (int ks = 0; ks < 2; ks++)
#pragma unroll
      for (int n = 0; n < NTW; n++) {
        const u16* bp = Bw +
            ((((size_t)((col0 + wc) >> 4) + n) * (K >> 5) + (k0 >> 5) + ks) * 4 + fg) * 128 +
            fr * 8;
        bfr[ks][n] = *(const bh8*)bp;
      }
    // prefetch next A tile into the other buffer (overlaps this tile's MFMA)
    if (ti + 1 < nk) STAGE((ti + 1) & 1, k0 + 64);
    const char* sA = smem + (ti & 1) * 16384;
#pragma unroll
    for (int ks = 0; ks < 2; ks++) {
      bh8 af[4];
#pragma unroll
      for (int m = 0; m < 4; m++) {
        int rr = wr + m * 16 + fr;
        af[m] = *(const bh8*)(sA + rr * 128 + ((ks * 64 + fg * 16) ^ ((rr & 7) << 4)));
      }
      __builtin_amdgcn_s_setprio(1);
#pragma unroll
      for (int m = 0; m < 4; m++)
#pragma unroll
        for (int n = 0; n < NTW; n++) acc[m][n] = mfma16(af[m], bfr[ks][n], acc[m][n]);
      __builtin_amdgcn_s_setprio(0);
    }
    __syncthreads();  // drains prefetch (vmcnt 0) + all waves done reading sA
  }
#pragma unroll
  for (int m = 0; m < 4; m++)
#pragma unroll
    for (int n = 0; n < NTW; n++)
#pragma unroll
      for (int r = 0; r < 4; r++) {
        int row = row0 + wr + m * 16 + fg * 4 + r;
        int col = col0 + wc + n * 16 + fr;
        float v = acc[m][n][r];
        if (mode == MODE_BF16) {
          ((u16*)Cp)[(size_t)row * N + col] = f2bf(v * scl);
        } else if (mode == MODE_RELU_BF16) {
          ((u16*)Cp)[(size_t)row * N + col] = f2bf(v > 0.f ? v : 0.f);
        } else {  // MODE_KV: scatter into fragment-major K2 / V2 layouts
          int bb = row >> 12, s = row & 4095;
          if (col < 512) {
            int h = col >> 6, dd = col & 63;
            ((u16*)Cp)[(((size_t)((bb * 8 + h) * 8 + (dd >> 3))) * SEQ + s) * 8 + (dd & 7)] = f2bf(v);
          } else {
            int dd2 = col - 512;
            int h = dd2 >> 6, dd = dd2 & 63;
            ((u16*)C2p)[(((size_t)((bb * 8 + h) * 512 + (s >> 3))) * 64 + dd) * 8 + (s & 7)] = f2bf(v);
          }
        }
      }
}

// ---------------- fused Q + KV projection (768 blocks) -------------------------
// T1 XCD placement: by = id % 64 (panel id), bx = id / 64 -> all blocks sharing
// an A-row-panel have ids congruent mod 8 -> land on the SAME XCD's L2.
__global__ __launch_bounds__(256) void qkv_kernel(
    const u16* __restrict__ xb, const u16* __restrict__ sb,
    const u16* __restrict__ wqb, const u16* __restrict__ wkvb,
    u16* __restrict__ Qb, u16* __restrict__ K2, u16* __restrict__ V2) {
  __shared__ __attribute__((aligned(16))) char smem[2 * 16384];
  int bid = blockIdx.x;
  if (bid < 256) {
    gemm_core<4>(smem, xb, xb, 512, wqb, Qb, nullptr, 512, 512, MODE_BF16, CEXP,
                 bid >> 6, bid & 63);
  } else {
    int kb = bid - 256;
    gemm_core<4>(smem, sb, sb, 512, wkvb, K2, V2, 1024, 512, MODE_KV, 1.0f,
                 kb >> 6, kb & 63);
  }
}

// ---------------- FFN1: relu((x|m) @ W1^T), concat-free ------------------------
// launched as 1-D grid of 512; by = id % 64 -> same-panel blocks on same XCD
__global__ __launch_bounds__(256) void ffn1_kernel(
    const u16* __restrict__ xb, const u16* __restrict__ m0ln,
    const u16* __restrict__ w1b, u16* __restrict__ h1) {
  __shared__ __attribute__((aligned(16))) char smem[2 * 16384];
  int bid = blockIdx.x;
  gemm_core<4>(smem, xb, m0ln, 512, w1b, h1, nullptr, 1024, 1024, MODE_RELU_BF16, 1.0f,
               bid >> 6, bid & 63);
}

// ---------------- N=512 GEMM (M0, FFN2): 128x64 tiles, 512 blocks --------------
__global__ __launch_bounds__(256) void gemm64_kernel(
    const u16* __restrict__ A, const u16* __restrict__ A2, int strideA,
    const u16* __restrict__ Bw, u16* __restrict__ Cp, int K, float scl) {
  __shared__ __attribute__((aligned(16))) char smem[2 * 16384];
  int bid = blockIdx.x;
  gemm_core<2>(smem, A, A2, strideA, Bw, Cp, nullptr, 512, K, MODE_BF16, scl,
               bid >> 6, bid & 63);
}

// ---------------- flash attention: LDS-free, SPLIT=1, in-kernel normalize ------
// grid 512 blocks (2/CU, reg-capped residency anyway): (b,h) x 32 qb.
// 4 waves x 32 q; no barriers; K2/V2 fragment-major -> every MFMA operand is a
// coalesced 16B/lane global load (L2-resident via XCD swizzle). Full-S per
// block -> l_run is complete -> normalize in epilogue (no merge kernel).
__global__ __launch_bounds__(256, 3) void attn_kernel(
    const u16* __restrict__ Q, const u16* __restrict__ K2,
    const u16* __restrict__ V2, u16* __restrict__ O) {
  const int tid = threadIdx.x;
  const int w = tid >> 6, l = tid & 63;
  const int l31 = l & 31, hi = l >> 5;

  // XCD c = dl%8 sees only bh in {2c,2c+1} -> KV (4MB) L2-resident per XCD
  int dl = blockIdx.x;
  int c = dl & 7, j = dl >> 3;
  int bh = 2 * c + (j >> 5);
  int qb = j & 31;
  const int b = bh >> 3, h = bh & 7;
  const int qr0 = b * SEQ + qb * 128 + w * 32;
  const int NT = SEQ / 64;

  bh8 qf[4];
#pragma unroll
  for (int ks = 0; ks < 4; ks++)
    qf[ks] = *(const bh8*)(Q + (size_t)(qr0 + l31) * DM + h * HD + ks * 16 + hi * 8);

  const u16* Kbase = K2 + (size_t)bh * 8 * SEQ * 8;   // [slot][s][8d]
  const u16* Vbase = V2 + (size_t)bh * 512 * 64 * 8;  // [sslot][d][8s]

  // persistent load pointers, bumped by constants each tile
  const u16* kp[4]; const u16* vp[4];
#pragma unroll
  for (int ks = 0; ks < 4; ks++) {
    kp[ks] = Kbase + ((size_t)(ks * 2 + hi) * SEQ + l31) * 8;
    vp[ks] = Vbase + ((size_t)(ks * 2 + hi) * 64 + l31) * 8;
  }

  fx16 o0, o1;
#pragma unroll
  for (int r = 0; r < 16; r++) { o0[r] = 0.f; o1[r] = 0.f; }
  float l_run = 0.f;

  for (int t = 0; t < NT; ++t) {
    bh8 kf0[4], kf1[4];
#pragma unroll
    for (int ks = 0; ks < 4; ks++) {
      kf0[ks] = *(const bh8*)kp[ks];
      kf1[ks] = *(const bh8*)(kp[ks] + 256);   // +32 s-rows
    }

    fx16 s0v, s1v;
#pragma unroll
    for (int r = 0; r < 16; r++) { s0v[r] = 0.f; s1v[r] = 0.f; }
    __builtin_amdgcn_s_setprio(1);
#pragma unroll
    for (int ks = 0; ks < 4; ks++) {
      s0v = mfma32(kf0[ks], qf[ks], s0v);
      s1v = mfma32(kf1[ks], qf[ks], s1v);
    }
    __builtin_amdgcn_s_setprio(0);

    bh8 vf0[4], vf1[4];
#pragma unroll
    for (int ks = 0; ks < 4; ks++) {
      vf0[ks] = *(const bh8*)vp[ks];
      vf1[ks] = *(const bh8*)(vp[ks] + 256);   // +32 d-rows
    }
#pragma unroll
    for (int ks = 0; ks < 4; ks++) { kp[ks] += 512; vp[ks] += 4096; }

    float rs = 0.f;
#pragma unroll
    for (int r = 0; r < 16; r++) {
      s0v[r] = __builtin_amdgcn_exp2f(s0v[r]); rs += s0v[r];
    }
#pragma unroll
    for (int r = 0; r < 16; r++) {
      s1v[r] = __builtin_amdgcn_exp2f(s1v[r]); rs += s1v[r];
    }
    l_run += rs;

    __builtin_amdgcn_s_setprio(1);
#pragma unroll
    for (int ks = 0; ks < 4; ks++) {
      int o8 = (ks & 1) * 8;
      u32 w0a, w1a, w0b, w1b;
      if (ks < 2) {
        w0a = cvtpk(s0v[o8 + 0], s0v[o8 + 1]);
        w1a = cvtpk(s0v[o8 + 2], s0v[o8 + 3]);
        w0b = cvtpk(s0v[o8 + 4], s0v[o8 + 5]);
        w1b = cvtpk(s0v[o8 + 6], s0v[o8 + 7]);
      } else {
        w0a = cvtpk(s1v[o8 + 0], s1v[o8 + 1]);
        w1a = cvtpk(s1v[o8 + 2], s1v[o8 + 3]);
        w0b = cvtpk(s1v[o8 + 4], s1v[o8 + 5]);
        w1b = cvtpk(s1v[o8 + 6], s1v[o8 + 7]);
      }
      pswap(w0a, w0b); pswap(w1a, w1b);
      u32x4 fw; fw.x = w0a; fw.y = w1a; fw.z = w0b; fw.w = w1b;
      bh8 pa = __builtin_bit_cast(bh8, fw);
      o0 = mfma32(pa, vf0[ks], o0);
      o1 = mfma32(pa, vf1[ks], o1);
    }
    __builtin_amdgcn_s_setprio(0);
  }

  // epilogue: l_run complete (full S) -> normalize and store directly
  l_run += __shfl_xor(l_run, 32);   // lane i now holds total l for q-col i&31
#pragma unroll
  for (int r = 0; r < 16; r++) {
    int crow = (r & 3) + 8 * (r >> 2) + 4 * hi;
    float li = 1.0f / __shfl(l_run, crow);
    size_t row = (size_t)(qr0 + crow);
    O[row * DM + h * HD + l31] = f2bf(o0[r] * li);
    O[row * DM + h * HD + 32 + l31] = f2bf(o1[r] * li);
  }
}

// ---------------- m0ln = LN(M0)*g1+b1: wave-per-row, row-major bf16 ------------
__global__ __launch_bounds__(256) void ln_kernel(
    const u16* __restrict__ M0, const float* __restrict__ g1,
    const float* __restrict__ b1, u16* __restrict__ out) {
  const int row = blockIdx.x * 4 + (threadIdx.x >> 6);
  const int lane = threadIdx.x & 63;
  bh8 v = *(const bh8*)(M0 + (size_t)row * 512 + lane * 8);
  float f[8], s = 0.f, s2 = 0.f;
#pragma unroll
  for (int j = 0; j < 8; j++) { f[j] = bf2f((u16)v[j]); s += f[j]; s2 += f[j] * f[j]; }
#pragma unroll
  for (int off = 1; off <= 32; off <<= 1) {
    s += __shfl_xor(s, off);
    s2 += __shfl_xor(s2, off);
  }
  float mu = s * (1.f / 512.f);
  float var = s2 * (1.f / 512.f) - mu * mu;
  float rstd = rsqrtf(var + 1e-5f);
  int col = lane * 8;
  bh8 o;
#pragma unroll
  for (int j = 0; j < 8; j++)
    o[j] = (short)f2bf((f[j] - mu) * rstd * g1[col + j] + b1[col + j]);
  *(bh8*)(out + (size_t)row * 512 + col) = o;
}

// ---------------- out = x + LN(f)*g2+b2: wave-per-row, fp32 out ----------------
__global__ __launch_bounds__(256) void ln_res_kernel(
    const u16* __restrict__ F, const float* __restrict__ X,
    const float* __restrict__ g2, const float* __restrict__ b2,
    float* __restrict__ out) {
  const int row = blockIdx.x * 4 + (threadIdx.x >> 6);
  const int lane = threadIdx.x & 63;
  bh8 v = *(const bh8*)(F + (size_t)row * 512 + lane * 8);
  float f[8], s = 0.f, s2 = 0.f;
#pragma unroll
  for (int j = 0; j < 8; j++) { f[j] = bf2f((u16)v[j]); s += f[j]; s2 += f[j] * f[j]; }
#pragma unroll
  for (int off = 1; off <= 32; off <<= 1) {
    s += __shfl_xor(s, off);
    s2 += __shfl_xor(s2, off);
  }
  float mu = s * (1.f / 512.f);
  float var = s2 * (1.f / 512.f) - mu * mu;
  float rstd = rsqrtf(var + 1e-5f);
  int col = lane * 8;
  const float* xr = X + (size_t)row * 512 + col;
  float* orow = out + (size_t)row * 512 + col;
#pragma unroll
  for (int j = 0; j < 8; j++)
    orow[j] = xr[j] + (f[j] - mu) * rstd * g2[col + j] + b2[col + j];
}

extern "C" void kernel_launch(void* const* d_in, const int* in_sizes, int n_in,
                              void* d_out, int out_size, void* d_ws, size_t ws_size,
                              hipStream_t stream) {
  (void)in_sizes; (void)n_in; (void)out_size; (void)ws_size;
  const float* x   = (const float*)d_in[0];
  const float* src = (const float*)d_in[1];
  const float* Wq  = (const float*)d_in[2];
  const float* Wk  = (const float*)d_in[3];
  const float* Wv  = (const float*)d_in[4];
  const float* Wm  = (const float*)d_in[5];
  const float* W1  = (const float*)d_in[6];
  const float* W2  = (const float*)d_in[7];
  const float* g1  = (const float*)d_in[8];
  const float* b1  = (const float*)d_in[9];
  const float* g2  = (const float*)d_in[10];
  const float* b2  = (const float*)d_in[11];

  char* ws = (char*)d_ws;
  u16* xb   = (u16*)(ws + 0);          // row-major bf16 x
  u16* sb   = (u16*)(ws + 8388608);    // row-major bf16 src
  u16* wqb  = (u16*)(ws + 16777216);   // frag-major weights
  u16* wkvb = (u16*)(ws + 17301504);
  u16* wmb  = (u16*)(ws + 18350080);
  u16* w1b  = (u16*)(ws + 18874368);
  u16* w2b  = (u16*)(ws + 20971520);
  u16* Qb   = (u16*)(ws + 22020096);   // row-major Q (pre-scaled by CEXP)
  u16* K2b  = (u16*)(ws + 30408704);   // attn fragment-major K
  u16* V2b  = (u16*)(ws + 38797312);   // attn fragment-major V
  u16* Ob   = (u16*)(ws + 47185920);   // attn output, row-major (normalized)

  u16* M0b  = (u16*)(ws + 30408704);   // aliases K2b (dead after attn)
  u16* m0ln = (u16*)(ws + 38797312);   // aliases V2b (dead after attn)
  u16* h1b  = (u16*)(ws + 22020096);   // 16MB, aliases Qb (dead after attn)
  u16* fb   = (u16*)(ws + 8388608);    // aliases sb (dead after qkv)

  cvt_all_kernel<<<2048, 256, 0, stream>>>(x, src, Wq, Wk, Wv, Wm, W1, W2,
                                           xb, sb, wqb, wkvb, wmb, w1b, w2b);
  qkv_kernel<<<768, 256, 0, stream>>>(xb, sb, wqb, wkvb, Qb, K2b, V2b);
  attn_kernel<<<512, 256, 0, stream>>>(Qb, K2b, V2b, Ob);
  gemm64_kernel<<<512, 256, 0, stream>>>(Ob, Ob, 512, wmb, M0b, 512, 1.0f);
  ln_kernel<<<2048, 256, 0, stream>>>(M0b, g1, b1, m0ln);
  ffn1_kernel<<<512, 256, 0, stream>>>(xb, m0ln, w1b, h1b);
  gemm64_kernel<<<512, 256, 0, stream>>>(h1b, h1b, 1024, w2b, fb, 1024, 1.0f);
  ln_res_kernel<<<2048, 256, 0, stream>>>(fb, x, g2, b2, (float*)d_out);
}